// Round 8
// baseline (306.618 us; speedup 1.0000x reference)
//
#include <hip/hip_runtime.h>
#include <math.h>

typedef __attribute__((ext_vector_type(4))) float f32x4;
typedef __attribute__((ext_vector_type(8))) short short8;
typedef __attribute__((ext_vector_type(4))) unsigned int u32x4;

#define KDIM  4096
#define NTOK  16384
#define BT    32           // tokens per block (2 halves x 16)
#define KSL   1024         // K per wave-slice (4 slices)
#define CH    (KSL/32)     // 32 chunks of K=32
#define DELTA 1.2e-4f

union S8U { u32x4 u; short8 s; };
__device__ inline short8 as_s8(u32x4 v) { S8U t; t.u = v; return t.s; }

struct HiLo { unsigned h, l; };

// split (x0,x1) into hi+lo bf16 (round-half-up), packed pairwise
__device__ inline HiLo splitpair(float x0, float x1) {
  unsigned u0 = __float_as_uint(x0) + 0x8000u;
  unsigned u1 = __float_as_uint(x1) + 0x8000u;
  HiLo r;
  r.h = (u0 >> 16) | (u1 & 0xffff0000u);
  float h0 = __uint_as_float(u0 & 0xffff0000u);
  float h1 = __uint_as_float(u1 & 0xffff0000u);
  float l0 = x0 - h0;
  float l1 = x1 - h1;
  unsigned v0 = __float_as_uint(l0) + 0x8000u;
  unsigned v1 = __float_as_uint(l1) + 0x8000u;
  r.l = (v0 >> 16) | (v1 & 0xffff0000u);
  return r;
}

// ---- prep: W [64][4096] f32 -> ws: per 8-elem group, 16B hi-bf16 + 16B lo-bf16
__global__ __launch_bounds__(512) void wsplit_kernel(
    const float* __restrict__ W, char* __restrict__ ws)
{
  int gid = blockIdx.x * 512 + threadIdx.x;      // 0..32767 (64 experts * 512 groups)
  const float* p = W + (size_t)gid * 8;
  f32x4 x0 = ((const f32x4*)p)[0];
  f32x4 x1 = ((const f32x4*)p)[1];
  u32x4 hi, lo;
  HiLo s;
  s = splitpair(x0[0], x0[1]); hi[0] = s.h; lo[0] = s.l;
  s = splitpair(x0[2], x0[3]); hi[1] = s.h; lo[1] = s.l;
  s = splitpair(x1[0], x1[1]); hi[2] = s.h; lo[2] = s.l;
  s = splitpair(x1[2], x1[3]); hi[3] = s.h; lo[3] = s.l;
  *(u32x4*)(ws + (size_t)gid * 32)      = hi;
  *(u32x4*)(ws + (size_t)gid * 32 + 16) = lo;
}

#define LOADA(st, c) do { \
  apf[st][0] = *(const f32x4*)(Arow + (size_t)(c) * 32); \
  apf[st][1] = *(const f32x4*)(Arow + (size_t)(c) * 32 + 4); \
} while (0)

#define LOADW(st, c) do { \
  _Pragma("unroll") \
  for (int nf_ = 0; nf_ < 4; ++nf_) { \
    wph[st][nf_] = *(const u32x4*)(Wbase + (size_t)nf_ * 262144 + (size_t)(c) * 128); \
    wpl[st][nf_] = *(const u32x4*)(Wbase + (size_t)nf_ * 262144 + (size_t)(c) * 128 + 16); \
  } \
} while (0)

// LOADW must come AFTER the MFMA cluster: the distance-2 prefetch lands in
// the SAME 2-deep slot consumed this step (WAR). A-path is safe (split
// consumes apf before LOADA).
#define STEP(J) do { \
  const int c_ = cc + (J); \
  u32x4 ah, al; \
  HiLo s0 = splitpair(apf[(J) & 3][0][0], apf[(J) & 3][0][1]); \
  HiLo s1 = splitpair(apf[(J) & 3][0][2], apf[(J) & 3][0][3]); \
  HiLo s2 = splitpair(apf[(J) & 3][1][0], apf[(J) & 3][1][1]); \
  HiLo s3 = splitpair(apf[(J) & 3][1][2], apf[(J) & 3][1][3]); \
  ah[0] = s0.h; al[0] = s0.l; ah[1] = s1.h; al[1] = s1.l; \
  ah[2] = s2.h; al[2] = s2.l; ah[3] = s3.h; al[3] = s3.l; \
  if (c_ + 4 < CH) LOADA((J) & 3, c_ + 4); \
  _Pragma("unroll") for (int nf = 0; nf < 4; ++nf) { \
    acc[nf] = __builtin_amdgcn_mfma_f32_16x16x32_bf16(as_s8(ah), as_s8(wph[(J) & 1][nf]), acc[nf], 0, 0, 0); \
    acc[nf] = __builtin_amdgcn_mfma_f32_16x16x32_bf16(as_s8(ah), as_s8(wpl[(J) & 1][nf]), acc[nf], 0, 0, 0); \
    acc[nf] = __builtin_amdgcn_mfma_f32_16x16x32_bf16(as_s8(al), as_s8(wph[(J) & 1][nf]), acc[nf], 0, 0, 0); \
  } \
  if (c_ + 2 < CH) LOADW((J) & 1, c_ + 2); \
} while (0)

__global__ __launch_bounds__(512, 4) void router_kernel(
    const float* __restrict__ H, const char* __restrict__ Ws,
    const float* __restrict__ W, float* __restrict__ out)
{
  __shared__ float  LG[4][BT][68];
  __shared__ double dlog[64];
  __shared__ int    refList[BT];
  __shared__ int    refCnt;

  const int tid  = threadIdx.x;
  const int lane = tid & 63;
  const int wv   = tid >> 6;   // 0..7
  const int th   = wv >> 2;    // token-half 0..1 (16 tokens each)
  const int kh   = wv & 3;     // K-slice 0..3
  const int l15  = lane & 15;
  const int kg   = lane >> 4;  // 0..3
  const int tb   = blockIdx.x * BT;

  if (tid == 0) refCnt = 0;

  const float* Arow  = H  + (size_t)(tb + th * 16 + l15) * KDIM + (size_t)kh * KSL + kg * 8;
  const char*  Wbase = Ws + (size_t)l15 * 16384 + (size_t)(kh * 128 + kg) * 32;

  f32x4 acc[4] = {};
  f32x4 apf[4][2];   // A prefetch: 4 stages x 8 floats
  u32x4 wph[2][4];   // W-hi prefetch: 2 stages x 4 expert-frags
  u32x4 wpl[2][4];

  LOADA(0, 0); LOADA(1, 1); LOADA(2, 2); LOADA(3, 3);
  LOADW(0, 0); LOADW(1, 1);

  #pragma unroll 1
  for (int cc = 0; cc < CH; cc += 4) {
    STEP(0); STEP(1); STEP(2); STEP(3);
  }

  // --- write per-slice logits; one barrier; reduce on read
  #pragma unroll
  for (int nf = 0; nf < 4; ++nf)
    #pragma unroll
    for (int r = 0; r < 4; ++r)
      LG[kh][th * 16 + kg * 4 + r][nf * 16 + l15] = acc[nf][r];
  __syncthreads();

  // --- top-8 per token (lane = expert); flag near-ties for f64 refine
  for (int t4 = 0; t4 < 4; ++t4) {
    int t = wv * 4 + t4;
    float x = ((LG[0][t][lane] + LG[1][t][lane]) + LG[2][t][lane]) + LG[3][t][lane];
    float m = x;
    #pragma unroll
    for (int off = 32; off > 0; off >>= 1)
      m = fmaxf(m, __shfl_xor(m, off, 64));
    float v = x;
    float selV = 0.f, sum = 0.f, prev = 0.f, gapmin = 1e30f;
    int   selI = 0;
    #pragma unroll
    for (int j = 0; j < 9; ++j) {   // top-9: 8 outputs + rank-9 gap
      float bv = v;
      int   bi = lane;
      #pragma unroll
      for (int off = 32; off > 0; off >>= 1) {
        float ov = __shfl_xor(bv, off, 64);
        int   oi = __shfl_xor(bi, off, 64);
        if (ov > bv || (ov == bv && oi < bi)) { bv = ov; bi = oi; }
      }
      if (j > 0) gapmin = fminf(gapmin, prev - bv);
      prev = bv;
      if (j < 8) {
        float e = __expf(bv - m);
        sum += e;
        if (lane == j) { selV = e; selI = bi; }
      }
      if (lane == bi) v = -INFINITY;
    }
    bool flag = (gapmin < DELTA);
    if (flag && lane == 0) {
      int p = atomicAdd(&refCnt, 1);
      refList[p] = t;
    }
    if (!flag && lane < 8) {
      int tgl = tb + t;
      out[(size_t)tgl * 8 + lane] = selV / sum;
      out[(size_t)NTOK * 8 + (size_t)tgl * 8 + lane] = (float)selI;
    }
  }
  __syncthreads();

  // --- f64 refine for flagged tokens (rare): exact ranking
  const int nref = refCnt;
  const int re = tid >> 3;   // expert 0..63
  const int rs = tid & 7;    // k-offset 0..7 (4 floats each per 32-float stride)
  for (int i = 0; i < nref; ++i) {
    const int t = refList[i];
    const float* hrow = H + (size_t)(tb + t) * KDIM;
    const float* wrw  = W + (size_t)re * KDIM;
    double accd = 0.0;
    for (int k0 = 0; k0 < KDIM; k0 += 32) {
      f32x4 hv = *reinterpret_cast<const f32x4*>(hrow + k0 + rs * 4);
      f32x4 wvv = *reinterpret_cast<const f32x4*>(wrw + k0 + rs * 4);
      #pragma unroll
      for (int j = 0; j < 4; ++j)
        accd = fma((double)hv[j], (double)wvv[j], accd);
    }
    accd += __shfl_xor(accd, 1, 64);
    accd += __shfl_xor(accd, 2, 64);
    accd += __shfl_xor(accd, 4, 64);
    if (rs == 0) dlog[re] = accd;
    __syncthreads();
    if (tid < 64) {   // wave 0: exact f64 top-8
      double x = dlog[tid];
      double m = x;
      #pragma unroll
      for (int off = 32; off > 0; off >>= 1)
        m = fmax(m, __shfl_xor(m, off, 64));
      double v = x, sum = 0.0, selV = 0.0;
      int selI = 0;
      #pragma unroll
      for (int j = 0; j < 8; ++j) {
        double bv = v;
        int    bi = tid;
        #pragma unroll
        for (int off = 32; off > 0; off >>= 1) {
          double ov = __shfl_xor(bv, off, 64);
          int    oi = __shfl_xor(bi, off, 64);
          if (ov > bv || (ov == bv && oi < bi)) { bv = ov; bi = oi; }
        }
        double e = exp(bv - m);
        sum += e;
        if (tid == j) { selV = e; selI = bi; }
        if (tid == bi) v = -1e300;
      }
      if (tid < 8) {
        int tgl = tb + t;
        out[(size_t)tgl * 8 + tid] = (float)(selV / sum);
        out[(size_t)NTOK * 8 + (size_t)tgl * 8 + tid] = (float)selI;
      }
    }
    __syncthreads();
  }
}

extern "C" void kernel_launch(void* const* d_in, const int* in_sizes, int n_in,
                              void* d_out, int out_size, void* d_ws, size_t ws_size,
                              hipStream_t stream) {
  const float* H = (const float*)d_in[0];   // [4,4096,4096] f32
  const float* W = (const float*)d_in[1];   // [64,4096] f32
  float* out = (float*)d_out;               // weights [16384*8] then idx [16384*8]
  char*  ws  = (char*)d_ws;                 // 1 MiB: pre-split W hi/lo bf16
  wsplit_kernel<<<64, 512, 0, stream>>>(W, ws);
  router_kernel<<<NTOK / BT, 512, 0, stream>>>(H, ws, W, out);
}

// Round 9
// 291.618 us; speedup vs baseline: 1.0514x; 1.0514x over previous
//
#include <hip/hip_runtime.h>
#include <math.h>

typedef __attribute__((ext_vector_type(4))) float f32x4;
typedef __attribute__((ext_vector_type(8))) short short8;
typedef __attribute__((ext_vector_type(4))) unsigned int u32x4;

#define KDIM  4096
#define NTOK  16384
#define BT    32           // tokens per block (2 halves x 16)
#define KSL   1024         // K per wave-slice (4 slices)
#define CH    (KSL/32)     // 32 chunks of K=32
#define DELTA 1.2e-4f

union S8U { u32x4 u; short8 s; };
__device__ inline short8 as_s8(u32x4 v) { S8U t; t.u = v; return t.s; }

struct HiLo { unsigned h, l; };

// split (x0,x1) into hi+lo bf16 (round-half-up), packed pairwise
__device__ inline HiLo splitpair(float x0, float x1) {
  unsigned u0 = __float_as_uint(x0) + 0x8000u;
  unsigned u1 = __float_as_uint(x1) + 0x8000u;
  HiLo r;
  r.h = (u0 >> 16) | (u1 & 0xffff0000u);
  float h0 = __uint_as_float(u0 & 0xffff0000u);
  float h1 = __uint_as_float(u1 & 0xffff0000u);
  float l0 = x0 - h0;
  float l1 = x1 - h1;
  unsigned v0 = __float_as_uint(l0) + 0x8000u;
  unsigned v1 = __float_as_uint(l1) + 0x8000u;
  r.l = (v0 >> 16) | (v1 & 0xffff0000u);
  return r;
}

// ---- prep: W [64][4096] f32 -> ws: per 8-elem group, 16B hi-bf16 + 16B lo-bf16
__global__ __launch_bounds__(512) void wsplit_kernel(
    const float* __restrict__ W, char* __restrict__ ws)
{
  int gid = blockIdx.x * 512 + threadIdx.x;      // 0..32767 (64 experts * 512 groups)
  const float* p = W + (size_t)gid * 8;
  f32x4 x0 = ((const f32x4*)p)[0];
  f32x4 x1 = ((const f32x4*)p)[1];
  u32x4 hi, lo;
  HiLo s;
  s = splitpair(x0[0], x0[1]); hi[0] = s.h; lo[0] = s.l;
  s = splitpair(x0[2], x0[3]); hi[1] = s.h; lo[1] = s.l;
  s = splitpair(x1[0], x1[1]); hi[2] = s.h; lo[2] = s.l;
  s = splitpair(x1[2], x1[3]); hi[3] = s.h; lo[3] = s.l;
  *(u32x4*)(ws + (size_t)gid * 32)      = hi;
  *(u32x4*)(ws + (size_t)gid * 32 + 16) = lo;
}

#define LOADA(st, c) do { \
  apf[st][0] = *(const f32x4*)(Arow + (size_t)(c) * 32); \
  apf[st][1] = *(const f32x4*)(Arow + (size_t)(c) * 32 + 4); \
} while (0)

#define LOADW(st, c) do { \
  _Pragma("unroll") \
  for (int nf_ = 0; nf_ < 4; ++nf_) { \
    wph[st][nf_] = *(const u32x4*)(Wbase + (size_t)nf_ * 262144 + (size_t)(c) * 128); \
    wpl[st][nf_] = *(const u32x4*)(Wbase + (size_t)nf_ * 262144 + (size_t)(c) * 128 + 16); \
  } \
} while (0)

// LOADW must come AFTER the MFMA cluster: the distance-2 prefetch lands in
// the SAME 2-deep slot consumed this step (WAR). A-path is safe (split
// consumes apf before LOADA).
#define STEP(J) do { \
  const int c_ = cc + (J); \
  u32x4 ah, al; \
  HiLo s0 = splitpair(apf[(J) & 3][0][0], apf[(J) & 3][0][1]); \
  HiLo s1 = splitpair(apf[(J) & 3][0][2], apf[(J) & 3][0][3]); \
  HiLo s2 = splitpair(apf[(J) & 3][1][0], apf[(J) & 3][1][1]); \
  HiLo s3 = splitpair(apf[(J) & 3][1][2], apf[(J) & 3][1][3]); \
  ah[0] = s0.h; al[0] = s0.l; ah[1] = s1.h; al[1] = s1.l; \
  ah[2] = s2.h; al[2] = s2.l; ah[3] = s3.h; al[3] = s3.l; \
  if (c_ + 4 < CH) LOADA((J) & 3, c_ + 4); \
  _Pragma("unroll") for (int nf = 0; nf < 4; ++nf) { \
    acc[nf] = __builtin_amdgcn_mfma_f32_16x16x32_bf16(as_s8(ah), as_s8(wph[(J) & 1][nf]), acc[nf], 0, 0, 0); \
    acc[nf] = __builtin_amdgcn_mfma_f32_16x16x32_bf16(as_s8(ah), as_s8(wpl[(J) & 1][nf]), acc[nf], 0, 0, 0); \
    acc[nf] = __builtin_amdgcn_mfma_f32_16x16x32_bf16(as_s8(al), as_s8(wph[(J) & 1][nf]), acc[nf], 0, 0, 0); \
  } \
  if (c_ + 2 < CH) LOADW((J) & 1, c_ + 2); \
} while (0)

__global__ __launch_bounds__(512, 2) void router_kernel(
    const float* __restrict__ H, const char* __restrict__ Ws,
    const float* __restrict__ W, float* __restrict__ out)
{
  __shared__ float  LG[4][BT][68];
  __shared__ double dlog[64];
  __shared__ int    refList[BT];
  __shared__ int    refCnt;

  const int tid  = threadIdx.x;
  const int lane = tid & 63;
  const int wv   = tid >> 6;   // 0..7
  const int th   = wv >> 2;    // token-half 0..1 (16 tokens each)
  const int kh   = wv & 3;     // K-slice 0..3
  const int l15  = lane & 15;
  const int kg   = lane >> 4;  // 0..3
  const int tb   = blockIdx.x * BT;

  if (tid == 0) refCnt = 0;

  const float* Arow  = H  + (size_t)(tb + th * 16 + l15) * KDIM + (size_t)kh * KSL + kg * 8;
  const char*  Wbase = Ws + (size_t)l15 * 16384 + (size_t)(kh * 128 + kg) * 32;

  f32x4 acc[4] = {};
  f32x4 apf[4][2];   // A prefetch: 4 stages x 8 floats
  u32x4 wph[2][4];   // W-hi prefetch: 2 stages x 4 expert-frags
  u32x4 wpl[2][4];

  LOADA(0, 0); LOADA(1, 1); LOADA(2, 2); LOADA(3, 3);
  LOADW(0, 0); LOADW(1, 1);

  #pragma unroll 1
  for (int cc = 0; cc < CH; cc += 4) {
    STEP(0); STEP(1); STEP(2); STEP(3);
  }

  // --- write per-slice logits; one barrier; reduce on read
  #pragma unroll
  for (int nf = 0; nf < 4; ++nf)
    #pragma unroll
    for (int r = 0; r < 4; ++r)
      LG[kh][th * 16 + kg * 4 + r][nf * 16 + l15] = acc[nf][r];
  __syncthreads();

  // --- top-8 per token (lane = expert); flag near-ties for f64 refine
  for (int t4 = 0; t4 < 4; ++t4) {
    int t = wv * 4 + t4;
    float x = ((LG[0][t][lane] + LG[1][t][lane]) + LG[2][t][lane]) + LG[3][t][lane];
    float m = x;
    #pragma unroll
    for (int off = 32; off > 0; off >>= 1)
      m = fmaxf(m, __shfl_xor(m, off, 64));
    float v = x;
    float selV = 0.f, sum = 0.f, prev = 0.f, gapmin = 1e30f;
    int   selI = 0;
    #pragma unroll
    for (int j = 0; j < 9; ++j) {   // top-9: 8 outputs + rank-9 gap
      float bv = v;
      int   bi = lane;
      #pragma unroll
      for (int off = 32; off > 0; off >>= 1) {
        float ov = __shfl_xor(bv, off, 64);
        int   oi = __shfl_xor(bi, off, 64);
        if (ov > bv || (ov == bv && oi < bi)) { bv = ov; bi = oi; }
      }
      if (j > 0) gapmin = fminf(gapmin, prev - bv);
      prev = bv;
      if (j < 8) {
        float e = __expf(bv - m);
        sum += e;
        if (lane == j) { selV = e; selI = bi; }
      }
      if (lane == bi) v = -INFINITY;
    }
    bool flag = (gapmin < DELTA);
    if (flag && lane == 0) {
      int p = atomicAdd(&refCnt, 1);
      refList[p] = t;
    }
    if (!flag && lane < 8) {
      int tgl = tb + t;
      out[(size_t)tgl * 8 + lane] = selV / sum;
      out[(size_t)NTOK * 8 + (size_t)tgl * 8 + lane] = (float)selI;
    }
  }
  __syncthreads();

  // --- f64 refine for flagged tokens (rare): exact ranking
  const int nref = refCnt;
  const int re = tid >> 3;   // expert 0..63
  const int rs = tid & 7;    // k-offset 0..7 (4 floats each per 32-float stride)
  for (int i = 0; i < nref; ++i) {
    const int t = refList[i];
    const float* hrow = H + (size_t)(tb + t) * KDIM;
    const float* wrw  = W + (size_t)re * KDIM;
    double accd = 0.0;
    for (int k0 = 0; k0 < KDIM; k0 += 32) {
      f32x4 hv = *reinterpret_cast<const f32x4*>(hrow + k0 + rs * 4);
      f32x4 wvv = *reinterpret_cast<const f32x4*>(wrw + k0 + rs * 4);
      #pragma unroll
      for (int j = 0; j < 4; ++j)
        accd = fma((double)hv[j], (double)wvv[j], accd);
    }
    accd += __shfl_xor(accd, 1, 64);
    accd += __shfl_xor(accd, 2, 64);
    accd += __shfl_xor(accd, 4, 64);
    if (rs == 0) dlog[re] = accd;
    __syncthreads();
    if (tid < 64) {   // wave 0: exact f64 top-8
      double x = dlog[tid];
      double m = x;
      #pragma unroll
      for (int off = 32; off > 0; off >>= 1)
        m = fmax(m, __shfl_xor(m, off, 64));
      double v = x, sum = 0.0, selV = 0.0;
      int selI = 0;
      #pragma unroll
      for (int j = 0; j < 8; ++j) {
        double bv = v;
        int    bi = tid;
        #pragma unroll
        for (int off = 32; off > 0; off >>= 1) {
          double ov = __shfl_xor(bv, off, 64);
          int    oi = __shfl_xor(bi, off, 64);
          if (ov > bv || (ov == bv && oi < bi)) { bv = ov; bi = oi; }
        }
        double e = exp(bv - m);
        sum += e;
        if (tid == j) { selV = e; selI = bi; }
        if (tid == bi) v = -1e300;
      }
      if (tid < 8) {
        int tgl = tb + t;
        out[(size_t)tgl * 8 + tid] = (float)(selV / sum);
        out[(size_t)NTOK * 8 + (size_t)tgl * 8 + tid] = (float)selI;
      }
    }
    __syncthreads();
  }
}

extern "C" void kernel_launch(void* const* d_in, const int* in_sizes, int n_in,
                              void* d_out, int out_size, void* d_ws, size_t ws_size,
                              hipStream_t stream) {
  const float* H = (const float*)d_in[0];   // [4,4096,4096] f32
  const float* W = (const float*)d_in[1];   // [64,4096] f32
  float* out = (float*)d_out;               // weights [16384*8] then idx [16384*8]
  char*  ws  = (char*)d_ws;                 // 1 MiB: pre-split W hi/lo bf16
  wsplit_kernel<<<64, 512, 0, stream>>>(W, ws);
  router_kernel<<<NTOK / BT, 512, 0, stream>>>(H, ws, W, out);
}

// Round 10
// 247.205 us; speedup vs baseline: 1.2403x; 1.1797x over previous
//
#include <hip/hip_runtime.h>
#include <math.h>

typedef __attribute__((ext_vector_type(4))) float f32x4;
typedef __attribute__((ext_vector_type(8))) short short8;
typedef __attribute__((ext_vector_type(4))) unsigned int u32x4;

#define KDIM  4096
#define NTOK  16384
#define BT    16            // tokens per block
#define BK    256           // K floats per staged chunk
#define NCH   (KDIM/BK)     // 16 chunks
#define AROW  1040          // padded row stride in bytes (1024 + 16)
#define BUFSZ (BT*AROW)     // 16640 B per buffer
#define DELTA 1.2e-4f

union S8U { u32x4 u; short8 s; };
__device__ inline short8 as_s8(u32x4 v) { S8U t; t.u = v; return t.s; }

struct HiLo { unsigned h, l; };

// split (x0,x1) into hi+lo bf16 (round-half-up), packed pairwise
__device__ inline HiLo splitpair(float x0, float x1) {
  unsigned u0 = __float_as_uint(x0) + 0x8000u;
  unsigned u1 = __float_as_uint(x1) + 0x8000u;
  HiLo r;
  r.h = (u0 >> 16) | (u1 & 0xffff0000u);
  float h0 = __uint_as_float(u0 & 0xffff0000u);
  float h1 = __uint_as_float(u1 & 0xffff0000u);
  float l0 = x0 - h0;
  float l1 = x1 - h1;
  unsigned v0 = __float_as_uint(l0) + 0x8000u;
  unsigned v1 = __float_as_uint(l1) + 0x8000u;
  r.l = (v0 >> 16) | (v1 & 0xffff0000u);
  return r;
}

__device__ inline void gload16(const void* g, void* l) {
  __builtin_amdgcn_global_load_lds(
      (const __attribute__((address_space(1))) unsigned int*)g,
      (__attribute__((address_space(3))) unsigned int*)l, 16, 0, 0);
}

// ---- prep: W [64][4096] f32 -> ws: per 8-elem group, 16B hi-bf16 + 16B lo-bf16
__global__ __launch_bounds__(512) void wsplit_kernel(
    const float* __restrict__ W, char* __restrict__ ws)
{
  int gid = blockIdx.x * 512 + threadIdx.x;      // 64 experts * 512 groups
  const float* p = W + (size_t)gid * 8;
  f32x4 x0 = ((const f32x4*)p)[0];
  f32x4 x1 = ((const f32x4*)p)[1];
  u32x4 hi, lo;
  HiLo s;
  s = splitpair(x0[0], x0[1]); hi[0] = s.h; lo[0] = s.l;
  s = splitpair(x0[2], x0[3]); hi[1] = s.h; lo[1] = s.l;
  s = splitpair(x1[0], x1[1]); hi[2] = s.h; lo[2] = s.l;
  s = splitpair(x1[2], x1[3]); hi[3] = s.h; lo[3] = s.l;
  *(u32x4*)(ws + (size_t)gid * 32)      = hi;
  *(u32x4*)(ws + (size_t)gid * 32 + 16) = lo;
}

__global__ __launch_bounds__(256, 2) void router_kernel(
    const float* __restrict__ H, const char* __restrict__ Ws,
    const float* __restrict__ W, float* __restrict__ out)
{
  // A double-buffer (2 x 16 rows x 1040B); LG overlays it after the main loop
  __shared__ __align__(16) char smem[2 * BUFSZ];
  __shared__ double dlog[64];
  __shared__ int    refList[BT];
  __shared__ int    refCnt;

  const int tid  = threadIdx.x;
  const int lane = tid & 63;
  const int wv   = tid >> 6;   // 0..3 = K-quarter
  const int kq   = wv;
  const int l15  = lane & 15;
  const int kg   = lane >> 4;  // 0..3
  const int tb   = blockIdx.x * BT;

  if (tid == 0) refCnt = 0;

  f32x4 acc[4] = {};

  // ---- stage chunk 0
  {
    #pragma unroll
    for (int q = 0; q < 4; ++q) {
      int row = wv * 4 + q;
      gload16(H + (size_t)(tb + row) * KDIM + lane * 4, smem + row * AROW);
    }
  }
  __syncthreads();

  // ---- main loop: stage c+1 (async DMA, no VGPRs) while computing c
  #pragma unroll 1
  for (int c = 0; c < NCH; ++c) {
    const int buf = c & 1;
    if (c + 1 < NCH) {
      #pragma unroll
      for (int q = 0; q < 4; ++q) {
        int row = wv * 4 + q;
        gload16(H + (size_t)(tb + row) * KDIM + (size_t)(c + 1) * BK + lane * 4,
                smem + (buf ^ 1) * BUFSZ + row * AROW);
      }
    }
    #pragma unroll
    for (int cg = 0; cg < 2; ++cg) {
      const char* ab = smem + buf * BUFSZ + l15 * AROW
                     + (kq * 256 + cg * 128 + kg * 32);
      f32x4 a0 = ((const f32x4*)ab)[0];
      f32x4 a1 = ((const f32x4*)ab)[1];
      u32x4 ah, al;
      HiLo s0 = splitpair(a0[0], a0[1]);
      HiLo s1 = splitpair(a0[2], a0[3]);
      HiLo s2 = splitpair(a1[0], a1[1]);
      HiLo s3 = splitpair(a1[2], a1[3]);
      ah[0] = s0.h; al[0] = s0.l; ah[1] = s1.h; al[1] = s1.l;
      ah[2] = s2.h; al[2] = s2.l; ah[3] = s3.h; al[3] = s3.l;
      const char* wb = Ws + (size_t)l15 * 16384
                     + (size_t)(c * 32 + kq * 8 + cg * 4 + kg) * 32;
      u32x4 wh0 = *(const u32x4*)(wb);
      u32x4 wl0 = *(const u32x4*)(wb + 16);
      u32x4 wh1 = *(const u32x4*)(wb + 262144);
      u32x4 wl1 = *(const u32x4*)(wb + 262144 + 16);
      u32x4 wh2 = *(const u32x4*)(wb + 2 * 262144);
      u32x4 wl2 = *(const u32x4*)(wb + 2 * 262144 + 16);
      u32x4 wh3 = *(const u32x4*)(wb + 3 * 262144);
      u32x4 wl3 = *(const u32x4*)(wb + 3 * 262144 + 16);
      acc[0] = __builtin_amdgcn_mfma_f32_16x16x32_bf16(as_s8(ah), as_s8(wh0), acc[0], 0, 0, 0);
      acc[0] = __builtin_amdgcn_mfma_f32_16x16x32_bf16(as_s8(ah), as_s8(wl0), acc[0], 0, 0, 0);
      acc[0] = __builtin_amdgcn_mfma_f32_16x16x32_bf16(as_s8(al), as_s8(wh0), acc[0], 0, 0, 0);
      acc[1] = __builtin_amdgcn_mfma_f32_16x16x32_bf16(as_s8(ah), as_s8(wh1), acc[1], 0, 0, 0);
      acc[1] = __builtin_amdgcn_mfma_f32_16x16x32_bf16(as_s8(ah), as_s8(wl1), acc[1], 0, 0, 0);
      acc[1] = __builtin_amdgcn_mfma_f32_16x16x32_bf16(as_s8(al), as_s8(wh1), acc[1], 0, 0, 0);
      acc[2] = __builtin_amdgcn_mfma_f32_16x16x32_bf16(as_s8(ah), as_s8(wh2), acc[2], 0, 0, 0);
      acc[2] = __builtin_amdgcn_mfma_f32_16x16x32_bf16(as_s8(ah), as_s8(wl2), acc[2], 0, 0, 0);
      acc[2] = __builtin_amdgcn_mfma_f32_16x16x32_bf16(as_s8(al), as_s8(wh2), acc[2], 0, 0, 0);
      acc[3] = __builtin_amdgcn_mfma_f32_16x16x32_bf16(as_s8(ah), as_s8(wh3), acc[3], 0, 0, 0);
      acc[3] = __builtin_amdgcn_mfma_f32_16x16x32_bf16(as_s8(ah), as_s8(wl3), acc[3], 0, 0, 0);
      acc[3] = __builtin_amdgcn_mfma_f32_16x16x32_bf16(as_s8(al), as_s8(wh3), acc[3], 0, 0, 0);
    }
    __syncthreads();   // drains vmcnt (stage c+1 complete) + LDS reads done
  }

  // ---- K-quarter reduce via LG (overlays smem; main loop ended with barrier)
  float (*LG)[BT][68] = (float (*)[BT][68])smem;
  #pragma unroll
  for (int nf = 0; nf < 4; ++nf)
    #pragma unroll
    for (int r = 0; r < 4; ++r)
      LG[kq][kg * 4 + r][nf * 16 + l15] = acc[nf][r];
  __syncthreads();

  // ---- top-8 per token (lane = expert); flag near-ties for f64 refine
  for (int t4 = 0; t4 < 4; ++t4) {
    int t = wv * 4 + t4;
    float x = ((LG[0][t][lane] + LG[1][t][lane]) + LG[2][t][lane]) + LG[3][t][lane];
    float m = x;
    #pragma unroll
    for (int off = 32; off > 0; off >>= 1)
      m = fmaxf(m, __shfl_xor(m, off, 64));
    float v = x;
    float selV = 0.f, sum = 0.f, prev = 0.f, gapmin = 1e30f;
    int   selI = 0;
    #pragma unroll
    for (int j = 0; j < 9; ++j) {   // top-9: 8 outputs + rank-9 gap
      float bv = v;
      int   bi = lane;
      #pragma unroll
      for (int off = 32; off > 0; off >>= 1) {
        float ov = __shfl_xor(bv, off, 64);
        int   oi = __shfl_xor(bi, off, 64);
        if (ov > bv || (ov == bv && oi < bi)) { bv = ov; bi = oi; }
      }
      if (j > 0) gapmin = fminf(gapmin, prev - bv);
      prev = bv;
      if (j < 8) {
        float e = __expf(bv - m);
        sum += e;
        if (lane == j) { selV = e; selI = bi; }
      }
      if (lane == bi) v = -INFINITY;
    }
    bool flag = (gapmin < DELTA);
    if (flag && lane == 0) {
      int p = atomicAdd(&refCnt, 1);
      refList[p] = t;
    }
    if (!flag && lane < 8) {
      int tgl = tb + t;
      out[(size_t)tgl * 8 + lane] = selV / sum;
      out[(size_t)NTOK * 8 + (size_t)tgl * 8 + lane] = (float)selI;
    }
  }
  __syncthreads();

  // ---- f64 refine for flagged tokens (rare): exact ranking
  const int nref = refCnt;
  const int re = tid >> 2;   // expert 0..63
  const int rs = tid & 3;    // k-offset: 4 floats per 16-float stride
  for (int i = 0; i < nref; ++i) {
    const int t = refList[i];
    const float* hrow = H + (size_t)(tb + t) * KDIM;
    const float* wrw  = W + (size_t)re * KDIM;
    double accd = 0.0;
    for (int k0 = 0; k0 < KDIM; k0 += 16) {
      f32x4 hv  = *reinterpret_cast<const f32x4*>(hrow + k0 + rs * 4);
      f32x4 wvv = *reinterpret_cast<const f32x4*>(wrw + k0 + rs * 4);
      #pragma unroll
      for (int j = 0; j < 4; ++j)
        accd = fma((double)hv[j], (double)wvv[j], accd);
    }
    accd += __shfl_xor(accd, 1, 64);
    accd += __shfl_xor(accd, 2, 64);
    if (rs == 0) dlog[re] = accd;
    __syncthreads();
    if (tid < 64) {   // wave 0: exact f64 top-8
      double x = dlog[tid];
      double m = x;
      #pragma unroll
      for (int off = 32; off > 0; off >>= 1)
        m = fmax(m, __shfl_xor(m, off, 64));
      double v = x, sum = 0.0, selV = 0.0;
      int selI = 0;
      #pragma unroll
      for (int j = 0; j < 8; ++j) {
        double bv = v;
        int    bi = tid;
        #pragma unroll
        for (int off = 32; off > 0; off >>= 1) {
          double ov = __shfl_xor(bv, off, 64);
          int    oi = __shfl_xor(bi, off, 64);
          if (ov > bv || (ov == bv && oi < bi)) { bv = ov; bi = oi; }
        }
        double e = exp(bv - m);
        sum += e;
        if (tid == j) { selV = e; selI = bi; }
        if (tid == bi) v = -1e300;
      }
      if (tid < 8) {
        int tgl = tb + t;
        out[(size_t)tgl * 8 + tid] = (float)(selV / sum);
        out[(size_t)NTOK * 8 + (size_t)tgl * 8 + tid] = (float)selI;
      }
    }
    __syncthreads();
  }
}

extern "C" void kernel_launch(void* const* d_in, const int* in_sizes, int n_in,
                              void* d_out, int out_size, void* d_ws, size_t ws_size,
                              hipStream_t stream) {
  const float* H = (const float*)d_in[0];   // [4,4096,4096] f32
  const float* W = (const float*)d_in[1];   // [64,4096] f32
  float* out = (float*)d_out;               // weights [16384*8] then idx [16384*8]
  char*  ws  = (char*)d_ws;                 // 1 MiB: pre-split W hi/lo bf16
  wsplit_kernel<<<64, 512, 0, stream>>>(W, ws);
  router_kernel<<<NTOK / BT, 256, 0, stream>>>(H, ws, W, out);
}